// Round 8
// baseline (403.879 us; speedup 1.0000x reference)
//
#include <hip/hip_runtime.h>
#include <hip/hip_bf16.h>

#define BB 8
#define TT 4
#define NN 4096
#define UU 64
#define EE 65536
#define BN (BB*NN)   // 32768
#define CAP 64
#define NEG 0.2f
#define SLP 68       // LDS row stride: 68*4=272 B, 16B-aligned rows

// ws layout (float offsets); hp/es/ed ping-pong by t parity
#define OFF_XT   0                      // 12*BN  (t,f,row)
#define OFF_HP0  (12*BN)                // BN*64 row-major h'
#define OFF_HP1  (OFF_HP0 + 64*BN)
#define OFF_ES0  (OFF_HP1 + 64*BN)     // BN
#define OFF_ES1  (OFF_ES0 + BN)
#define OFF_ED0  (OFF_ES1 + BN)
#define OFF_ED1  (OFF_ED0 + BN)
#define OFF_CNT  (OFF_ED1 + BN)        // NN ints
#define OFF_SLOT (OFF_CNT + NN)        // NN*CAP ints (ends ~19.9 MB)

__global__ __launch_bounds__(256) void k_conv_x(const float* x, float* xT) {
  int i = blockIdx.x * 256 + threadIdx.x;     // < 12*BN
  int r = i & (BN - 1);
  int tf = i >> 15;
  int t = tf / 3, f = tf - 3 * t;
  int b = r >> 12, n = r & (NN - 1);
  xT[i] = x[(((b * TT + t) * NN + n) * 3) + f];
}

__global__ __launch_bounds__(256) void k_fill(const int* src, const int* dst,
                                              int* cnt, int* slot) {
  int i = blockIdx.x * 256 + threadIdx.x;
  if (i < EE) {
    int d = dst[i];
    int p = atomicAdd(&cnt[d], 1);
    if (p < CAP) slot[d * CAP + p] = src[i];
  } else if (i < EE + NN) {
    int n = i - EE;
    int p = atomicAdd(&cnt[n], 1);
    if (p < CAP) slot[n * CAP + p] = n;
  }
}

// GAT at t=0 (h == 0): h' = x_0 @ gat_W[64:67]; es/ed. Writes buffer 0.
__global__ __launch_bounds__(512) void k_gat0(float* ws, const float* gW,
                                              const float* as_, const float* ad_) {
  const float* xT = ws + OFF_XT;
  float* hp = ws + OFF_HP0;
  float* es = ws + OFF_ES0;
  float* ed = ws + OFF_ED0;
  int wave = __builtin_amdgcn_readfirstlane(threadIdx.x >> 6);
  int lane = threadIdx.x & 63;
  int row = blockIdx.x * 64 + lane;
  int u0 = wave * 8;
  float acc[8];
#pragma unroll
  for (int j = 0; j < 8; ++j) acc[j] = 0.f;
#pragma unroll
  for (int k = 0; k < 3; ++k) {
    float ck = xT[k * BN + row];   // t=0
#pragma unroll
    for (int j = 0; j < 8; ++j) acc[j] += ck * gW[(64 + k) * 64 + u0 + j];
  }
  float esa = 0.f, eda = 0.f;
#pragma unroll
  for (int j = 0; j < 8; ++j) {
    esa += acc[j] * as_[u0 + j];
    eda += acc[j] * ad_[u0 + j];
  }
  float4* o = (float4*)(hp + (size_t)row * 64 + u0);
  o[0] = make_float4(acc[0], acc[1], acc[2], acc[3]);
  o[1] = make_float4(acc[4], acc[5], acc[6], acc[7]);
  __shared__ float esL[8][64], edL[8][64];
  esL[wave][lane] = esa;
  edL[wave][lane] = eda;
  __syncthreads();
  if (wave == 0) {
    float s = 0.f;
#pragma unroll
    for (int w = 0; w < 8; ++w) s += esL[w][lane];
    es[row] = s;
  } else if (wave == 1) {
    float s = 0.f;
#pragma unroll
    for (int w = 0; w < 8; ++w) s += edL[w][lane];
    ed[row] = s;
  }
}

// dot-accumulate 8 rows against one 16-wide weight chunk from LDS tile
#define CHUNK_ACC(TILE, WPTR, WSTRIDE, KOFF)                                   \
  {                                                                            \
    float wc[16];                                                              \
    _Pragma("unroll") for (int j = 0; j < 16; ++j)                             \
        wc[j] = (WPTR)[((KOFF) + j) * (WSTRIDE) + wcol];                       \
    _Pragma("unroll") for (int r = 0; r < 8; ++r) {                            \
      const float4* s4 = (const float4*)&TILE[r0 + r][c * 16];                 \
      float4 a0 = s4[0], a1 = s4[1], a2 = s4[2], a3 = s4[3];                   \
      acc[r] += a0.x * wc[0] + a0.y * wc[1] + a0.z * wc[2] + a0.w * wc[3] +    \
                a1.x * wc[4] + a1.y * wc[5] + a1.z * wc[6] + a1.w * wc[7] +    \
                a2.x * wc[8] + a2.y * wc[9] + a2.z * wc[10] + a2.w * wc[11] +  \
                a3.x * wc[12] + a3.y * wc[13] + a3.z * wc[14] + a3.w * wc[15]; \
    }                                                                          \
  }

// Fused step: attn(t) -> GRU(t) -> [GAT(t+1) | out head].
// 512 thr, 8 waves, 64 rows/block, grid = 512. lane = u; each wave owns rows
// wave*8..wave*8+7 end-to-end (no cross-wave deps except xS and out-head).
__global__ __launch_bounds__(512) void k_step(
    float* ws, const float* gb, const float* g1W, const float* g1b,
    const float* g2W, const float* g2b, const float* gW, const float* as_,
    const float* ad_, const float* oW, const float* ob, float* out, int t,
    int last) {
  const float* xT = ws + OFF_XT;
  int pr = t & 1;
  const float* hpR = ws + (pr ? OFF_HP1 : OFF_HP0);
  const float* esR = ws + (pr ? OFF_ES1 : OFF_ES0);
  const float* edR = ws + (pr ? OFF_ED1 : OFF_ED0);
  float* hpW = ws + (pr ? OFF_HP0 : OFF_HP1);
  float* esW = ws + (pr ? OFF_ES0 : OFF_ES1);
  float* edW = ws + (pr ? OFF_ED0 : OFF_ED1);
  const int* cnt = (const int*)(ws + OFF_CNT);
  const int* slot = (const int*)(ws + OFF_SLOT);

  int wave = __builtin_amdgcn_readfirstlane(threadIdx.x >> 6);
  int lane = threadIdx.x & 63;
  int rowbase = blockIdx.x * 64;
  int b = rowbase / NN;
  int nbase = rowbase - b * NN;
  __shared__ float sL[64][SLP];    // [row_local][u]
  __shared__ float rsL[64][SLP];   // [row_local][u]
  __shared__ float xS[6][64];      // [t:3 | t+1:3][row_local]

  // stage x for step t (and t+1 if not last)
  if (threadIdx.x < 384) {
    int k = threadIdx.x >> 6;          // 0..5
    int r = threadIdx.x & 63;
    int tt = t + (k >= 3 ? 1 : 0);
    int f = (k >= 3) ? k - 3 : k;
    if (tt < TT) xS[k][r] = xT[(tt * 3 + f) * BN + rowbase + r];
  }

  float gbv = gb[lane];   // lane = u

  // ---- P1: attention, 8 rows per wave; write sL[row][u] ----
#pragma unroll 1
  for (int rr = 0; rr < 8; ++rr) {
    int lr = wave * 8 + rr;
    int n = nbase + lr;
    int grow = b * NN + n;
    int deg = min(cnt[n], CAP);
    float edv = edR[grow];
    int sl = (lane < deg) ? slot[n * CAP + lane] : 0;
    float e;
    if (lane < deg) {
      e = esR[b * NN + sl] + edv;
      e = e > 0.f ? e : NEG * e;
    } else {
      e = -1e30f;
    }
    float m = e;
#pragma unroll
    for (int o = 32; o >= 1; o >>= 1) m = fmaxf(m, __shfl_xor(m, o, 64));
    float w = (lane < deg) ? __expf(e - m) : 0.f;
    float dsum = w;
#pragma unroll
    for (int o = 32; o >= 1; o >>= 1) dsum += __shfl_xor(dsum, o, 64);
    w *= 1.f / dsum;
    float acc = 0.f;
#pragma unroll 1
    for (int i0 = 0; i0 < deg; i0 += 8) {
      int sis[8];
      float wv[8];
#pragma unroll
      for (int j = 0; j < 8; ++j) {
        int i = i0 + j;
        sis[j] = __shfl(sl, i, 64);
        float t_ = __shfl(w, i, 64);
        wv[j] = (i < deg) ? t_ : 0.f;
      }
      float v[8];
#pragma unroll
      for (int j = 0; j < 8; ++j)
        v[j] = hpR[(size_t)(b * NN + sis[j]) * 64 + lane];
#pragma unroll
      for (int j = 0; j < 8; ++j) acc += wv[j] * v[j];
    }
    sL[lr][lane] = acc + gbv;
  }
  __syncthreads();   // covers xS staging (sL rows are wave-private)

  int r0 = wave * 8;
  int wcol = lane;
  float acc[8];

  // ---- P2: r gate (g1W col = lane) ----
  {
    float wx0 = g1W[0 * 128 + lane], wx1 = g1W[1 * 128 + lane],
          wx2 = g1W[2 * 128 + lane];
#pragma unroll
    for (int r = 0; r < 8; ++r) {
      int lr = r0 + r;
      acc[r] = xS[0][lr] * wx0 + xS[1][lr] * wx1 + xS[2][lr] * wx2;
    }
#pragma unroll 1
    for (int c = 0; c < 4; ++c) CHUNK_ACC(sL, g1W, 128, 3 + c * 16)
    float g1bv = g1b[lane];
#pragma unroll
    for (int r = 0; r < 8; ++r) {
      int lr = r0 + r;
      float rg = 1.f / (1.f + __expf(-(acc[r] + g1bv)));
      rsL[lr][lane] = rg * sL[lr][lane];
    }
  }

  // ---- P3a: u gate (g1W col = 64+lane) ----
  float ug[8];
  {
    wcol = 64 + lane;
    float wx0 = g1W[0 * 128 + wcol], wx1 = g1W[1 * 128 + wcol],
          wx2 = g1W[2 * 128 + wcol];
#pragma unroll
    for (int r = 0; r < 8; ++r) {
      int lr = r0 + r;
      acc[r] = xS[0][lr] * wx0 + xS[1][lr] * wx1 + xS[2][lr] * wx2;
    }
#pragma unroll 1
    for (int c = 0; c < 4; ++c) CHUNK_ACC(sL, g1W, 128, 3 + c * 16)
    float g1bu = g1b[64 + lane];
#pragma unroll
    for (int r = 0; r < 8; ++r) ug[r] = 1.f / (1.f + __expf(-(acc[r] + g1bu)));
  }

  // ---- P3b: candidate on rs (g2W col = lane); then h -> sL ----
  {
    wcol = lane;
    float wx0 = g2W[0 * 64 + lane], wx1 = g2W[1 * 64 + lane],
          wx2 = g2W[2 * 64 + lane];
#pragma unroll
    for (int r = 0; r < 8; ++r) {
      int lr = r0 + r;
      acc[r] = xS[0][lr] * wx0 + xS[1][lr] * wx1 + xS[2][lr] * wx2;
    }
#pragma unroll 1
    for (int c = 0; c < 4; ++c) CHUNK_ACC(rsL, g2W, 64, 3 + c * 16)
    float g2bv = g2b[lane];
#pragma unroll
    for (int r = 0; r < 8; ++r) {
      int lr = r0 + r;
      float z = acc[r] + g2bv;
      float c = 1.f - 2.f / (__expf(2.f * z) + 1.f);
      float h = ug[r] * sL[lr][lane] + (1.f - ug[r]) * c;
      sL[lr][lane] = h;   // wave-private rows: no barrier needed
    }
  }

  if (!last) {
    // ---- P5: GAT(t+1); gW rows 0..63 = h (sL), 64..66 = x ----
    float wx0 = gW[64 * 64 + lane], wx1 = gW[65 * 64 + lane],
          wx2 = gW[66 * 64 + lane];
#pragma unroll
    for (int r = 0; r < 8; ++r) {
      int lr = r0 + r;
      acc[r] = xS[3][lr] * wx0 + xS[4][lr] * wx1 + xS[5][lr] * wx2;
    }
#pragma unroll 1
    for (int c = 0; c < 4; ++c) CHUNK_ACC(sL, gW, 64, c * 16)
    float asv = as_[lane], adv = ad_[lane];
#pragma unroll 1
    for (int r = 0; r < 8; ++r) {
      int lr = r0 + r;
      float a = acc[r];
      hpW[(size_t)(rowbase + lr) * 64 + lane] = a;
      float pe = a * asv, pd = a * adv;
#pragma unroll
      for (int o = 32; o >= 1; o >>= 1) {
        pe += __shfl_xor(pe, o, 64);
        pd += __shfl_xor(pd, o, 64);
      }
      if (lane == 0) {
        esW[rowbase + lr] = pe;
        edW[rowbase + lr] = pd;
      }
    }
  } else {
    // ---- P5': output head out[row,:] = h . oW + ob ----
    __syncthreads();   // out-head reads all rows (cross-wave)
    if (wave < 3) {
      float a = ob[wave];
#pragma unroll 8
      for (int k = 0; k < 64; ++k) a += sL[lane][k] * oW[k * 3 + wave];
      out[(size_t)(rowbase + lane) * 3 + wave] = a;
    }
  }
}

extern "C" void kernel_launch(void* const* d_in, const int* in_sizes, int n_in,
                              void* d_out, int out_size, void* d_ws, size_t ws_size,
                              hipStream_t stream) {
  const float* x = (const float*)d_in[0];
  const int* src = (const int*)d_in[1];
  const int* dst = (const int*)d_in[2];
  const float* gatW = (const float*)d_in[3];
  const float* asrc = (const float*)d_in[4];
  const float* adst = (const float*)d_in[5];
  const float* gatb = (const float*)d_in[6];
  const float* g1W = (const float*)d_in[7];
  const float* g1b = (const float*)d_in[8];
  const float* g2W = (const float*)d_in[9];
  const float* g2b = (const float*)d_in[10];
  const float* oW = (const float*)d_in[11];
  const float* ob = (const float*)d_in[12];
  float* ws = (float*)d_ws;
  float* out = (float*)d_out;

  hipMemsetAsync(ws + OFF_CNT, 0, NN * sizeof(int), stream);
  k_conv_x<<<(12 * BN) / 256, 256, 0, stream>>>(x, ws + OFF_XT);
  k_fill<<<(EE + NN) / 256, 256, 0, stream>>>(src, dst, (int*)(ws + OFF_CNT),
                                              (int*)(ws + OFF_SLOT));
  k_gat0<<<BN / 64, 512, 0, stream>>>(ws, gatW, asrc, adst);
  for (int t = 0; t < TT; ++t) {
    k_step<<<BN / 64, 512, 0, stream>>>(ws, gatb, g1W, g1b, g2W, g2b, gatW,
                                        asrc, adst, oW, ob, out, t,
                                        t == TT - 1 ? 1 : 0);
  }
}

// Round 9
// 303.278 us; speedup vs baseline: 1.3317x; 1.3317x over previous
//
#include <hip/hip_runtime.h>
#include <hip/hip_bf16.h>

#define BB 8
#define TT 4
#define NN 4096
#define UU 64
#define EE 65536
#define BN (BB*NN)   // 32768
#define CAP 64
#define NEG 0.2f

// ws layout (float offsets); hp/es/ed ping-pong by t parity
#define OFF_XT   0                      // 12*BN  (t,f,row)
#define OFF_HP0  (12*BN)                // BN*64 row-major h'
#define OFF_HP1  (OFF_HP0 + 64*BN)
#define OFF_ES0  (OFF_HP1 + 64*BN)     // BN
#define OFF_ES1  (OFF_ES0 + BN)
#define OFF_ED0  (OFF_ES1 + BN)
#define OFF_ED1  (OFF_ED0 + BN)
#define OFF_CNT  (OFF_ED1 + BN)        // NN ints
#define OFF_SLOT (OFF_CNT + NN)        // NN*CAP ints (ends ~19.9 MB)

#define NB_CONV ((12*BN)/256)          // 1536
#define NB_FILL ((EE+NN)/256)          // 260

// fused setup: xT transpose staging + slot-table build
__global__ __launch_bounds__(256) void k_setup(const float* x, const int* src,
                                               const int* dst, float* ws) {
  int blk = blockIdx.x;
  if (blk < NB_CONV) {
    int i = blk * 256 + threadIdx.x;    // < 12*BN
    int r = i & (BN - 1);
    int tf = i >> 15;
    int t = tf / 3, f = tf - 3 * t;
    int b = r >> 12, n = r & (NN - 1);
    ws[OFF_XT + i] = x[(((b * TT + t) * NN + n) * 3) + f];
  } else {
    int i = (blk - NB_CONV) * 256 + threadIdx.x;
    int* cnt = (int*)(ws + OFF_CNT);
    int* slot = (int*)(ws + OFF_SLOT);
    if (i < EE) {
      int d = dst[i];
      int p = atomicAdd(&cnt[d], 1);
      if (p < CAP) slot[d * CAP + p] = src[i];
    } else if (i < EE + NN) {
      int n = i - EE;
      int p = atomicAdd(&cnt[n], 1);
      if (p < CAP) slot[n * CAP + p] = n;
    }
  }
}

// GAT at t=0 (h == 0): h' = x_0 @ gat_W[64:67]; es/ed. Writes buffer 0.
__global__ __launch_bounds__(512) void k_gat0(float* ws, const float* gW,
                                              const float* as_, const float* ad_) {
  const float* xT = ws + OFF_XT;
  float* hp = ws + OFF_HP0;
  float* es = ws + OFF_ES0;
  float* ed = ws + OFF_ED0;
  int wave = __builtin_amdgcn_readfirstlane(threadIdx.x >> 6);
  int lane = threadIdx.x & 63;
  int row = blockIdx.x * 64 + lane;
  int u0 = wave * 8;
  float acc[8];
#pragma unroll
  for (int j = 0; j < 8; ++j) acc[j] = 0.f;
#pragma unroll
  for (int k = 0; k < 3; ++k) {
    float ck = xT[k * BN + row];   // t=0
#pragma unroll
    for (int j = 0; j < 8; ++j) acc[j] += ck * gW[(64 + k) * 64 + u0 + j];
  }
  float esa = 0.f, eda = 0.f;
#pragma unroll
  for (int j = 0; j < 8; ++j) {
    esa += acc[j] * as_[u0 + j];
    eda += acc[j] * ad_[u0 + j];
  }
  float4* o = (float4*)(hp + (size_t)row * 64 + u0);
  o[0] = make_float4(acc[0], acc[1], acc[2], acc[3]);
  o[1] = make_float4(acc[4], acc[5], acc[6], acc[7]);
  __shared__ float esL[8][64], edL[8][64];
  esL[wave][lane] = esa;
  edL[wave][lane] = eda;
  __syncthreads();
  if (wave == 0) {
    float s = 0.f;
#pragma unroll
    for (int w = 0; w < 8; ++w) s += esL[w][lane];
    es[row] = s;
  } else if (wave == 1) {
    float s = 0.f;
#pragma unroll
    for (int w = 0; w < 8; ++w) s += edL[w][lane];
    ed[row] = s;
  }
}

// Fused step: attn(t) -> GRU(t) -> [GAT(t+1) | out head].
// 512 thr, 8 waves, 64 rows/block, grid = 512. LDS tiles are [u][row];
// GEMM phases use lane=row, 8 u-outputs/thread, wave-uniform weights (s_load).
__global__ __launch_bounds__(512) void k_step(
    float* ws, const float* gb, const float* g1W, const float* g1b,
    const float* g2W, const float* g2b, const float* gW, const float* as_,
    const float* ad_, const float* oW, const float* ob, float* out, int t,
    int last) {
  const float* xT = ws + OFF_XT;
  int pr = t & 1;
  const float* hpR = ws + (pr ? OFF_HP1 : OFF_HP0);
  const float* esR = ws + (pr ? OFF_ES1 : OFF_ES0);
  const float* edR = ws + (pr ? OFF_ED1 : OFF_ED0);
  float* hpW = ws + (pr ? OFF_HP0 : OFF_HP1);
  float* esW = ws + (pr ? OFF_ES0 : OFF_ES1);
  float* edW = ws + (pr ? OFF_ED0 : OFF_ED1);
  const int* cnt = (const int*)(ws + OFF_CNT);
  const int* slot = (const int*)(ws + OFF_SLOT);

  int wave = __builtin_amdgcn_readfirstlane(threadIdx.x >> 6);
  int lane = threadIdx.x & 63;
  int rowbase = blockIdx.x * 64;
  int b = rowbase / NN;
  int nbase = rowbase - b * NN;
  __shared__ float sL[64][65];     // [u][row_local]
  __shared__ float rsL[64][65];    // [u][row_local]
  __shared__ float redA[8][64], redB[8][64];
  float gbv = gb[lane];   // lane = u during P1

  // ---- P1 prefetch: cnt/ed (uniform -> sgpr), slot/es (per-lane) for 8 rows
  int deg8[8];
  float edv8[8];
  int sl8[8];
  float e8[8];
#pragma unroll
  for (int rr = 0; rr < 8; ++rr) {
    int n = nbase + wave * 8 + rr;
    int d = min(cnt[n], CAP);
    deg8[rr] = d;
    edv8[rr] = edR[b * NN + n];
    sl8[rr] = (lane < d) ? slot[n * CAP + lane] : 0;
  }
#pragma unroll
  for (int rr = 0; rr < 8; ++rr) {
    float e;
    if (lane < deg8[rr]) {
      e = esR[b * NN + sl8[rr]] + edv8[rr];
      e = e > 0.f ? e : NEG * e;
    } else {
      e = -1e30f;
    }
    e8[rr] = e;
  }

  // ---- P1: attention, 8 rows per wave; write sL[u][row] (transposed) ----
#pragma unroll 1
  for (int rr = 0; rr < 8; ++rr) {
    int lr = wave * 8 + rr;
    int deg = deg8[rr];
    float e = e8[rr];
    float m = e;
#pragma unroll
    for (int o = 32; o >= 1; o >>= 1) m = fmaxf(m, __shfl_xor(m, o, 64));
    float w = (lane < deg) ? __expf(e - m) : 0.f;
    float dsum = w;
#pragma unroll
    for (int o = 32; o >= 1; o >>= 1) dsum += __shfl_xor(dsum, o, 64);
    w *= 1.f / dsum;
    int sl = sl8[rr];
    float acc = 0.f;
#pragma unroll 1
    for (int i0 = 0; i0 < deg; i0 += 16) {
      int sis[16];
      float wv[16];
#pragma unroll
      for (int j = 0; j < 16; ++j) {
        int i = i0 + j;
        sis[j] = __shfl(sl, i, 64);
        float t_ = __shfl(w, i, 64);
        wv[j] = (i < deg) ? t_ : 0.f;
      }
      float v[16];
#pragma unroll
      for (int j = 0; j < 16; ++j)
        v[j] = hpR[(size_t)(b * NN + sis[j]) * 64 + lane];
#pragma unroll
      for (int j = 0; j < 16; ++j) acc += wv[j] * v[j];
    }
    sL[lane][lr] = acc + gbv;
  }
  __syncthreads();   // B1

  int row = rowbase + lane;   // lane = row from here on
  int u0 = wave * 8;
  float xv[3];
#pragma unroll
  for (int k = 0; k < 3; ++k) xv[k] = xT[(t * 3 + k) * BN + row];

  // ---- P2+P3a fused: r gate AND u gate share the sL reads ----
  float accR[8], accU[8];
#pragma unroll
  for (int j = 0; j < 8; ++j) {
    accR[j] = xv[0] * g1W[0 * 128 + u0 + j] + xv[1] * g1W[1 * 128 + u0 + j] +
              xv[2] * g1W[2 * 128 + u0 + j];
    accU[j] = xv[0] * g1W[0 * 128 + 64 + u0 + j] +
              xv[1] * g1W[1 * 128 + 64 + u0 + j] +
              xv[2] * g1W[2 * 128 + 64 + u0 + j];
  }
#pragma unroll 8
  for (int k = 0; k < 64; ++k) {
    float sk = sL[k][lane];
#pragma unroll
    for (int j = 0; j < 8; ++j) {
      accR[j] += sk * g1W[(3 + k) * 128 + u0 + j];
      accU[j] += sk * g1W[(3 + k) * 128 + 64 + u0 + j];
    }
  }
  float sv[8], ug[8];
#pragma unroll
  for (int j = 0; j < 8; ++j) sv[j] = sL[u0 + j][lane];
#pragma unroll
  for (int j = 0; j < 8; ++j) {
    float rg = 1.f / (1.f + __expf(-(accR[j] + g1b[u0 + j])));
    rsL[u0 + j][lane] = rg * sv[j];
    ug[j] = 1.f / (1.f + __expf(-(accU[j] + g1b[64 + u0 + j])));
  }
  __syncthreads();   // B2

  // ---- P3b: candidate on rs; h = ug*s + (1-ug)*tanh ----
  float accC[8];
#pragma unroll
  for (int j = 0; j < 8; ++j)
    accC[j] = xv[0] * g2W[0 * 64 + u0 + j] + xv[1] * g2W[1 * 64 + u0 + j] +
              xv[2] * g2W[2 * 64 + u0 + j];
#pragma unroll 8
  for (int k = 0; k < 64; ++k) {
    float rk = rsL[k][lane];
#pragma unroll
    for (int j = 0; j < 8; ++j) accC[j] += rk * g2W[(3 + k) * 64 + u0 + j];
  }
#pragma unroll
  for (int j = 0; j < 8; ++j) {
    float z = accC[j] + g2b[u0 + j];
    float c = 1.f - 2.f / (__expf(2.f * z) + 1.f);
    float h = ug[j] * sv[j] + (1.f - ug[j]) * c;
    sL[u0 + j][lane] = h;   // safe: all sL reads finished before B2
  }
  __syncthreads();   // B3

  if (!last) {
    // ---- P5: GAT(t+1) on in-LDS h ----
    float xw[3];
#pragma unroll
    for (int k = 0; k < 3; ++k) xw[k] = xT[((t + 1) * 3 + k) * BN + row];
    float accG[8];
#pragma unroll
    for (int j = 0; j < 8; ++j)
      accG[j] = xw[0] * gW[64 * 64 + u0 + j] + xw[1] * gW[65 * 64 + u0 + j] +
                xw[2] * gW[66 * 64 + u0 + j];
#pragma unroll 8
    for (int k = 0; k < 64; ++k) {
      float hk = sL[k][lane];
#pragma unroll
      for (int j = 0; j < 8; ++j) accG[j] += hk * gW[k * 64 + u0 + j];
    }
    float esa = 0.f, eda = 0.f;
#pragma unroll
    for (int j = 0; j < 8; ++j) {
      esa += accG[j] * as_[u0 + j];
      eda += accG[j] * ad_[u0 + j];
    }
    float4* o = (float4*)(hpW + (size_t)row * 64 + u0);
    o[0] = make_float4(accG[0], accG[1], accG[2], accG[3]);
    o[1] = make_float4(accG[4], accG[5], accG[6], accG[7]);
    redA[wave][lane] = esa;
    redB[wave][lane] = eda;
    __syncthreads();
    if (wave == 0) {
      float s = 0.f;
#pragma unroll
      for (int w = 0; w < 8; ++w) s += redA[w][lane];
      esW[row] = s;
    } else if (wave == 1) {
      float s = 0.f;
#pragma unroll
      for (int w = 0; w < 8; ++w) s += redB[w][lane];
      edW[row] = s;
    }
  } else {
    // ---- P5': output head out[row,:] = h . oW + ob ----
    if (wave < 3) {
      float a = ob[wave];
#pragma unroll 8
      for (int k = 0; k < 64; ++k) a += sL[k][lane] * oW[k * 3 + wave];
      out[(size_t)row * 3 + wave] = a;
    }
  }
}

extern "C" void kernel_launch(void* const* d_in, const int* in_sizes, int n_in,
                              void* d_out, int out_size, void* d_ws, size_t ws_size,
                              hipStream_t stream) {
  const float* x = (const float*)d_in[0];
  const int* src = (const int*)d_in[1];
  const int* dst = (const int*)d_in[2];
  const float* gatW = (const float*)d_in[3];
  const float* asrc = (const float*)d_in[4];
  const float* adst = (const float*)d_in[5];
  const float* gatb = (const float*)d_in[6];
  const float* g1W = (const float*)d_in[7];
  const float* g1b = (const float*)d_in[8];
  const float* g2W = (const float*)d_in[9];
  const float* g2b = (const float*)d_in[10];
  const float* oW = (const float*)d_in[11];
  const float* ob = (const float*)d_in[12];
  float* ws = (float*)d_ws;
  float* out = (float*)d_out;

  hipMemsetAsync(ws + OFF_CNT, 0, NN * sizeof(int), stream);
  k_setup<<<NB_CONV + NB_FILL, 256, 0, stream>>>(x, src, dst, ws);
  k_gat0<<<BN / 64, 512, 0, stream>>>(ws, gatW, asrc, adst);
  for (int t = 0; t < TT; ++t) {
    k_step<<<BN / 64, 512, 0, stream>>>(ws, gatb, g1W, g1b, g2W, g2b, gatW,
                                        asrc, adst, oW, ob, out, t,
                                        t == TT - 1 ? 1 : 0);
  }
}